// Round 1
// baseline (840.021 us; speedup 1.0000x reference)
//
#include <hip/hip_runtime.h>
#include <math.h>

#define D 8192
#define KWTA_K 1024

__device__ __forceinline__ float softplus_f(float z) {
    // stable log1p(exp(z)) == max(z,0) + log1p(exp(-|z|))
    return fmaxf(z, 0.0f) + log1pf(expf(-fabsf(z)));
}

// ---------------- K1: x = rmsnorm(x_in + pred) * g ----------------
__global__ __launch_bounds__(1024) void k_rmsnorm(
    const float* __restrict__ x_in, const float* __restrict__ pred,
    const float* __restrict__ g, float* __restrict__ x) {
    __shared__ float red[16];
    __shared__ float s_scale;
    int tid = threadIdx.x;
    const float4* xi = (const float4*)x_in;
    const float4* pr = (const float4*)pred;
    float4 a0 = xi[tid];        float4 b0 = pr[tid];
    float4 a1 = xi[tid + 1024]; float4 b1 = pr[tid + 1024];
    float4 s0 = make_float4(a0.x + b0.x, a0.y + b0.y, a0.z + b0.z, a0.w + b0.w);
    float4 s1 = make_float4(a1.x + b1.x, a1.y + b1.y, a1.z + b1.z, a1.w + b1.w);
    float ss = s0.x*s0.x + s0.y*s0.y + s0.z*s0.z + s0.w*s0.w
             + s1.x*s1.x + s1.y*s1.y + s1.z*s1.z + s1.w*s1.w;
    #pragma unroll
    for (int off = 32; off; off >>= 1) ss += __shfl_down(ss, off, 64);
    if ((tid & 63) == 0) red[tid >> 6] = ss;
    __syncthreads();
    if (tid == 0) {
        float t = 0.0f;
        #pragma unroll
        for (int j = 0; j < 16; j++) t += red[j];
        s_scale = 1.0f / sqrtf(t / (float)D + 1e-6f);
    }
    __syncthreads();
    float sc = s_scale;
    const float4* gg = (const float4*)g;
    float4 g0 = gg[tid], g1 = gg[tid + 1024];
    float4 o0 = make_float4(s0.x*sc*g0.x, s0.y*sc*g0.y, s0.z*sc*g0.z, s0.w*sc*g0.w);
    float4 o1 = make_float4(s1.x*sc*g1.x, s1.y*sc*g1.y, s1.z*sc*g1.z, s1.w*sc*g1.w);
    ((float4*)x)[tid] = o0;
    ((float4*)x)[tid + 1024] = o1;
}

// ---------------- K2: rkv = [Wr@x ; Wk@x ; Wv@x], wave-per-row ----------------
__global__ __launch_bounds__(256) void k_rkv(
    const float* __restrict__ Wr, const float* __restrict__ Wk,
    const float* __restrict__ Wv, const float* __restrict__ x,
    float* __restrict__ out) {
    __shared__ float4 xs[D / 4];
    const float4* x4 = (const float4*)x;
    for (int t = threadIdx.x; t < D / 4; t += 256) xs[t] = x4[t];
    __syncthreads();
    int wave = threadIdx.x >> 6, lane = threadIdx.x & 63;
    int row_global = blockIdx.x * 4 + wave;   // 0 .. 3*D-1
    int m = row_global >> 13;                  // which matrix
    int r = row_global & (D - 1);
    const float* W = (m == 0) ? Wr : ((m == 1) ? Wk : Wv);
    const float4* Wrow = (const float4*)(W + (size_t)r * D);
    float ax = 0.0f, ay = 0.0f, az = 0.0f, aw = 0.0f;
    #pragma unroll 8
    for (int j = lane; j < D / 4; j += 64) {
        float4 w4 = Wrow[j];
        float4 xv = xs[j];
        ax += w4.x * xv.x; ay += w4.y * xv.y;
        az += w4.z * xv.z; aw += w4.w * xv.w;
    }
    float acc = (ax + ay) + (az + aw);
    #pragma unroll
    for (int off = 32; off; off >>= 1) acc += __shfl_down(acc, off, 64);
    if (lane == 0) out[row_global] = acc;
}

// ---------------- K3: elementwise cell update -> y ----------------
__global__ __launch_bounds__(256) void k_cell(
    const float* __restrict__ rkv,
    const float* __restrict__ state_num, const float* __restrict__ state_den,
    const float* __restrict__ state_var, const float* __restrict__ raw_decay,
    const float* __restrict__ pn_param, const float* __restrict__ on_param,
    const float* __restrict__ step_pos, const float* __restrict__ W_time,
    float* __restrict__ y) {
    int i = blockIdx.x * blockDim.x + threadIdx.x;
    const float* rp = rkv;
    const float* kk = rkv + D;
    const float* vv = rkv + 2 * D;
    float k = kk[i];
    float vi;
    if (i < 32) {  // RoPE over first 16 pairs
        int m = i >> 1;
        float theta = step_pos[0] * W_time[m];
        float c = cosf(theta), s = sinf(theta);
        float v0 = vv[2 * m], v1 = vv[2 * m + 1];
        vi = (i & 1) ? (v0 * s + v1 * c) : (v0 * c - v1 * s);
    } else {
        vi = vv[i];
    }
    float sp_d  = softplus_f(raw_decay[i]);
    float rate  = fmaxf(-sp_d, -30.0f);
    float lam   = fmaxf(expf(rate), 1e-6f);
    float pn    = fminf(fmaxf(softplus_f(pn_param[0]), 1e-6f), 10000.0f);
    float on    = fminf(fmaxf(softplus_f(on_param[0]), 1e-6f), 10000.0f);
    float sn    = state_num[i] * lam;
    float sd    = state_den[i] * lam;
    float sv    = state_var[i] * lam * lam + pn;
    float w     = expf(fminf(k, 30.0f));
    float ps    = sn / (sd + 1e-6f);
    float msg   = w * vi;
    float resid = msg - ps;
    float obs   = expf(fminf(-k, 30.0f)) * on + 1e-6f;
    float gain  = fminf(fmaxf(sv / (sv + obs), 1e-6f), 1.0f - 1e-6f);
    float ns    = ps + gain * resid;
    float r     = 1.0f / (1.0f + expf(-rp[i]));
    y[i] = r * ns;
}

// ---------------- K4: h = x + Wo @ y, wave-per-row ----------------
__global__ __launch_bounds__(256) void k_wo(
    const float* __restrict__ Wo, const float* __restrict__ y,
    const float* __restrict__ x, float* __restrict__ h) {
    __shared__ float4 ys[D / 4];
    const float4* y4 = (const float4*)y;
    for (int t = threadIdx.x; t < D / 4; t += 256) ys[t] = y4[t];
    __syncthreads();
    int wave = threadIdx.x >> 6, lane = threadIdx.x & 63;
    int row = blockIdx.x * 4 + wave;
    const float4* Wrow = (const float4*)(Wo + (size_t)row * D);
    float ax = 0.0f, ay = 0.0f, az = 0.0f, aw = 0.0f;
    #pragma unroll 8
    for (int j = lane; j < D / 4; j += 64) {
        float4 w4 = Wrow[j];
        float4 yv = ys[j];
        ax += w4.x * yv.x; ay += w4.y * yv.y;
        az += w4.z * yv.z; aw += w4.w * yv.w;
    }
    float acc = (ax + ay) + (az + aw);
    #pragma unroll
    for (int off = 32; off; off >>= 1) acc += __shfl_down(acc, off, 64);
    if (lane == 0) h[row] = x[row] + acc;
}

// ---------------- K5: exact top-K threshold + mask ----------------
__global__ __launch_bounds__(1024) void k_select(
    const float* __restrict__ h, float* __restrict__ out) {
    __shared__ int red[16];
    int tid = threadIdx.x;
    const float4* h4 = (const float4*)h;
    float4 a = h4[tid], b = h4[tid + 1024];
    float vals[8] = {a.x, a.y, a.z, a.w, b.x, b.y, b.z, b.w};
    unsigned keys[8];
    #pragma unroll
    for (int j = 0; j < 8; j++) {
        unsigned bits = __float_as_uint(vals[j]);
        keys[j] = (bits & 0x80000000u) ? ~bits : (bits | 0x80000000u);
    }
    // binary search max t with count(keys >= t) >= KWTA_K (t is an existing key)
    unsigned long long lo = 0ull, hi = 0xFFFFFFFFull;
    while (lo < hi) {
        unsigned mid = (unsigned)((lo + hi + 1ull) >> 1);
        int cnt = 0;
        #pragma unroll
        for (int j = 0; j < 8; j++) cnt += (keys[j] >= mid) ? 1 : 0;
        #pragma unroll
        for (int off = 32; off; off >>= 1) cnt += __shfl_down(cnt, off, 64);
        if ((tid & 63) == 0) red[tid >> 6] = cnt;
        __syncthreads();
        int total = 0;
        #pragma unroll
        for (int j = 0; j < 16; j++) total += red[j];
        if (total >= KWTA_K) lo = mid; else hi = (unsigned long long)mid - 1ull;
        __syncthreads();
    }
    unsigned kstar = (unsigned)lo;
    unsigned tb = (kstar & 0x80000000u) ? (kstar & 0x7FFFFFFFu) : ~kstar;
    float thresh = __uint_as_float(tb);
    float4 o0, o1;
    o0.x = (vals[0] >= thresh) ? vals[0] : 0.0f;
    o0.y = (vals[1] >= thresh) ? vals[1] : 0.0f;
    o0.z = (vals[2] >= thresh) ? vals[2] : 0.0f;
    o0.w = (vals[3] >= thresh) ? vals[3] : 0.0f;
    o1.x = (vals[4] >= thresh) ? vals[4] : 0.0f;
    o1.y = (vals[5] >= thresh) ? vals[5] : 0.0f;
    o1.z = (vals[6] >= thresh) ? vals[6] : 0.0f;
    o1.w = (vals[7] >= thresh) ? vals[7] : 0.0f;
    ((float4*)out)[tid] = o0;
    ((float4*)out)[tid + 1024] = o1;
}

extern "C" void kernel_launch(void* const* d_in, const int* in_sizes, int n_in,
                              void* d_out, int out_size, void* d_ws, size_t ws_size,
                              hipStream_t stream) {
    const float* x_in      = (const float*)d_in[0];
    const float* step_pos  = (const float*)d_in[1];
    const float* pred      = (const float*)d_in[2];
    const float* state_num = (const float*)d_in[3];
    const float* state_den = (const float*)d_in[4];
    const float* state_var = (const float*)d_in[5];
    const float* Wr        = (const float*)d_in[6];
    const float* Wk        = (const float*)d_in[7];
    const float* Wv        = (const float*)d_in[8];
    const float* Wo        = (const float*)d_in[9];
    const float* raw_decay = (const float*)d_in[10];
    const float* pn_param  = (const float*)d_in[11];
    const float* on_param  = (const float*)d_in[12];
    const float* g_norm    = (const float*)d_in[13];
    const float* W_time    = (const float*)d_in[14];
    float* out = (float*)d_out;

    float* ws  = (float*)d_ws;
    float* x   = ws;            // D
    float* rkv = ws + D;        // 3*D
    float* y   = ws + 4 * D;    // D
    float* h   = ws + 5 * D;    // D

    k_rmsnorm<<<1, 1024, 0, stream>>>(x_in, pred, g_norm, x);
    k_rkv<<<(3 * D) / 4, 256, 0, stream>>>(Wr, Wk, Wv, x, rkv);
    k_cell<<<D / 256, 256, 0, stream>>>(rkv, state_num, state_den, state_var,
                                        raw_decay, pn_param, on_param,
                                        step_pos, W_time, y);
    k_wo<<<D / 4, 256, 0, stream>>>(Wo, y, x, h);
    k_select<<<1, 1024, 0, stream>>>(h, out);
}